// Round 12
// baseline (120.354 us; speedup 1.0000x reference)
//
#include <hip/hip_runtime.h>

typedef _Float16 half8 __attribute__((ext_vector_type(8)));
typedef _Float16 half4 __attribute__((ext_vector_type(4)));
typedef float f32x4 __attribute__((ext_vector_type(4)));

namespace {

constexpr int HEADS = 8;
constexpr int BATCH = 512;
constexpr int DH    = 1024;
constexpr int CHW   = 8192;

__device__ __forceinline__ int xcd_swz(int bid, int nwg) {
  const int q = nwg >> 3;  // grids are %8 == 0
  return (bid & 7) * q + (bid >> 3);
}

typedef __attribute__((address_space(3))) unsigned int lds_u32;
typedef const __attribute__((address_space(1))) unsigned int glb_u32;
__device__ __forceinline__ void gl_lds16(const void* g, void* l) {
  __builtin_amdgcn_global_load_lds((glb_u32*)g, (lds_u32*)l, 16, 0, 0);
}

__device__ __forceinline__ half4 cvt4(float4 a) {
  half4 r;
  r[0] = (_Float16)a.x; r[1] = (_Float16)a.y; r[2] = (_Float16)a.z; r[3] = (_Float16)a.w;
  return r;
}

// ---------------------------------------------------------------------------
// PACK: X (3x 512x8192 f32) and W (3x 8x1024x1024 f32) -> f16 tiles.
// Tile = 128 rows x 64 cols = 8192 halves (16 KB), stored with the XOR
// bank-swizzle baked in: tile[row*64 + (cb^(row&7))*8 + hi] = nat[row][cb*8+hi].
// Source reads are LINEAR full rows (coalesced float4) -> HBM streams.
//   Wp[z][h][et=8][kt=16][8192]   Xp[z][h][nt=4][kt=16][8192]
// ---------------------------------------------------------------------------
__global__ __launch_bounds__(256) void pack_kernel(
    const float* __restrict__ Xq, const float* __restrict__ Xk, const float* __restrict__ Xv,
    const float* __restrict__ W1, const float* __restrict__ W2, const float* __restrict__ W3,
    _Float16* __restrict__ Xp, _Float16* __restrict__ Wp) {
  const int l = xcd_swz(blockIdx.x, 288);
  const int t = threadIdx.x;
  const int kt = t >> 4;              // 16 threads per k-tile-slice
  const int cbn = (t & 15) >> 1;      // natural 8-half block within tile row
  const int hi  = (t & 1) * 4;        // half4 position within the block
  const float* src;
  size_t srcStride;
  _Float16* dstBase;
  if (l < 192) {  // W: (z,h,et), panel 128 rows x 1024 f32, rows contiguous
    const int z = l >> 6, rem = l & 63, h = rem >> 3, et = rem & 7;
    const float* W = (z == 0) ? W1 : (z == 1) ? W2 : W3;
    src = W + (size_t)h * DH * DH + (size_t)et * 128 * DH + t * 4;
    srcStride = DH;
    dstBase = Wp + ((((size_t)z * 8 + h) * 8 + et) * 16 + kt) * 8192;
  } else {        // X: (z,h,nt), 128 rows x 1024 f32, rows at CHW stride
    const int l2 = l - 192;
    const int z = l2 >> 5, rem = l2 & 31, h = rem >> 2, nt = rem & 3;
    const float* X = (z == 0) ? Xq : (z == 1) ? Xk : Xv;
    src = X + (size_t)nt * 128 * CHW + (size_t)h * DH + t * 4;
    srcStride = CHW;
    dstBase = Xp + ((((size_t)z * 8 + h) * 4 + nt) * 16 + kt) * 8192;
  }
#pragma unroll 1
  for (int r = 0; r < 128; r += 4) {
    float4 v0 = *(const float4*)(src + (size_t)(r + 0) * srcStride);
    float4 v1 = *(const float4*)(src + (size_t)(r + 1) * srcStride);
    float4 v2 = *(const float4*)(src + (size_t)(r + 2) * srcStride);
    float4 v3 = *(const float4*)(src + (size_t)(r + 3) * srcStride);
    *(half4*)&dstBase[(r + 0) * 64 + (cbn ^ ((r + 0) & 7)) * 8 + hi] = cvt4(v0);
    *(half4*)&dstBase[(r + 1) * 64 + (cbn ^ ((r + 1) & 7)) * 8 + hi] = cvt4(v1);
    *(half4*)&dstBase[(r + 2) * 64 + (cbn ^ ((r + 2) & 7)) * 8 + hi] = cvt4(v2);
    *(half4*)&dstBase[(r + 3) * 64 + (cbn ^ ((r + 3) & 7)) * 8 + hi] = cvt4(v3);
  }
}

// ---------------------------------------------------------------------------
// f16 GEMM core on PACKED tiles: each K-step stages ONE contiguous 16-KB
// block per operand via global_load_lds (fully linear source). 128x128 tile,
// BK=64, 2 barriers/K-step, 32 KB LDS. ds_read applies the baked XOR.
// ---------------------------------------------------------------------------
template <int NT>
__device__ __forceinline__ void gemm16p_core(
    const char* ga, const char* gb,
    _Float16* As, _Float16* Bs,
    int tid, int wr, int wc, int lr, int lk, f32x4 (&acc)[4][4]) {
  const int off0 = tid * 16, off1 = 4096 + tid * 16;
  const int off2 = 8192 + tid * 16, off3 = 12288 + tid * 16;
#pragma unroll 1
  for (int t = 0; t < NT; ++t) {
    __syncthreads();
    gl_lds16(ga + off0, (char*)As + off0); gl_lds16(gb + off0, (char*)Bs + off0);
    gl_lds16(ga + off1, (char*)As + off1); gl_lds16(gb + off1, (char*)Bs + off1);
    gl_lds16(ga + off2, (char*)As + off2); gl_lds16(gb + off2, (char*)Bs + off2);
    gl_lds16(ga + off3, (char*)As + off3); gl_lds16(gb + off3, (char*)Bs + off3);
    ga += 16384; gb += 16384;
    __syncthreads();
    half8 a0[4], a1[4], b0[4], b1[4];
#pragma unroll
    for (int i = 0; i < 4; ++i) {
      const int row = wr + i * 16 + lr;
      a0[i] = *(const half8*)&As[row * 64 + ((lk    ) ^ (row & 7)) * 8];
      a1[i] = *(const half8*)&As[row * 64 + ((4 + lk) ^ (row & 7)) * 8];
    }
#pragma unroll
    for (int j = 0; j < 4; ++j) {
      const int row = wc + j * 16 + lr;
      b0[j] = *(const half8*)&Bs[row * 64 + ((lk    ) ^ (row & 7)) * 8];
      b1[j] = *(const half8*)&Bs[row * 64 + ((4 + lk) ^ (row & 7)) * 8];
    }
#pragma unroll
    for (int i = 0; i < 4; ++i)
#pragma unroll
      for (int j = 0; j < 4; ++j) {
        acc[i][j] = __builtin_amdgcn_mfma_f32_16x16x32_f16(a0[i], b0[j], acc[i][j], 0, 0, 0);
        acc[i][j] = __builtin_amdgcn_mfma_f32_16x16x32_f16(a1[i], b1[j], acc[i][j], 0, 0, 0);
      }
  }
}

// ---------------------------------------------------------------------------
// Fused Q/K/V projection on packed inputs. Outputs packed:
//   Qp/Kp[h][nt=4][kte=16][8192]   Vp[h][et=8][ktm=8][8192]
// ---------------------------------------------------------------------------
__global__ __launch_bounds__(256) void proj_kernel(
    const _Float16* __restrict__ Xp, const _Float16* __restrict__ Wp,
    const float* __restrict__ b1, const float* __restrict__ b2, const float* __restrict__ b3,
    _Float16* __restrict__ Qp, _Float16* __restrict__ Kp, _Float16* __restrict__ Vp) {
  __shared__ __align__(16) _Float16 As[128 * 64];
  __shared__ __align__(16) _Float16 Bs[128 * 64];
  const int tid = threadIdx.x;
  const int l  = xcd_swz(blockIdx.x, 768);
  const int z  = l >> 8, rem = l & 255;
  const int h  = rem >> 5, bx = rem & 31;
  const int tm = bx & 3, tn = bx >> 2;   // tm: n-tile (4), tn: e-tile (8)
  const float* bias = (z == 0) ? b1 : (z == 1) ? b2 : b3;

  const int lane = tid & 63, w = tid >> 6;
  const int wr = (w >> 1) * 64, wc = (w & 1) * 64;
  const int lr = lane & 15, lk = lane >> 4;

  const char* ga = (const char*)(Xp + ((((size_t)z * 8 + h) * 4 + tm) * 16) * 8192);
  const char* gb = (const char*)(Wp + ((((size_t)z * 8 + h) * 8 + tn) * 16) * 8192);

  f32x4 acc[4][4] = {};
  gemm16p_core<16>(ga, gb, As, Bs, tid, wr, wc, lr, lk, acc);

  if (z != 2) {
    _Float16* P = (z == 0) ? Qp : Kp;
#pragma unroll
    for (int i = 0; i < 4; ++i)
#pragma unroll
      for (int j = 0; j < 4; ++j) {
        const int colj = wc + j * 16 + lr;         // e within 128-tile
        const int e = tn * 128 + colj;
        const float bb = bias[h * DH + e];
        const int kte = tn * 2 + (colj >> 6);
        const int c64 = colj & 63;
        const int cbn = c64 >> 3;
#pragma unroll
        for (int q = 0; q < 4; ++q) {
          const int row = wr + i * 16 + lk * 4 + q;  // n within 128-tile
          const float val = acc[i][j][q] + bb;
          P[(((size_t)h * 4 + tm) * 16 + kte) * 8192 +
            row * 64 + ((cbn ^ (row & 7)) * 8) + (c64 & 7)] = (_Float16)val;
        }
      }
  } else {
#pragma unroll
    for (int i = 0; i < 4; ++i)
#pragma unroll
      for (int j = 0; j < 4; ++j) {
        const int row_v = wc + j * 16 + lr;        // e within 128-tile (Vp row)
        const float bb = bias[h * DH + tn * 128 + row_v];
#pragma unroll
        for (int q = 0; q < 4; ++q) {
          const int n = tm * 128 + wr + i * 16 + lk * 4 + q;  // global m index
          const float val = acc[i][j][q] + bb;
          const int c64 = n & 63;
          const int cbn = c64 >> 3;
          Vp[(((size_t)h * 8 + tn) * 8 + (n >> 6)) * 8192 +
             row_v * 64 + ((cbn ^ (row_v & 7)) * 8) + (n & 7)] = (_Float16)val;
        }
      }
  }
}

// S[h,n,m] = 32 * sum_e Q[n,e] K[m,e]  (fp32 natural rows, for softmax)
__global__ __launch_bounds__(256) void score_kernel(
    const _Float16* __restrict__ Qp, const _Float16* __restrict__ Kp,
    float* __restrict__ S) {
  __shared__ __align__(16) _Float16 As[128 * 64];
  __shared__ __align__(16) _Float16 Bs[128 * 64];
  const int tid = threadIdx.x;
  const int l  = xcd_swz(blockIdx.x, 128);
  const int h  = l >> 4, bx = l & 15;
  const int tm = bx & 3, tn = bx >> 2;   // n-tile, m-tile
  const int lane = tid & 63, w = tid >> 6;
  const int wr = (w >> 1) * 64, wc = (w & 1) * 64;
  const int lr = lane & 15, lk = lane >> 4;

  const char* ga = (const char*)(Qp + (((size_t)h * 4 + tm) * 16) * 8192);
  const char* gb = (const char*)(Kp + (((size_t)h * 4 + tn) * 16) * 8192);

  f32x4 acc[4][4] = {};
  gemm16p_core<16>(ga, gb, As, Bs, tid, wr, wc, lr, lk, acc);

#pragma unroll
  for (int i = 0; i < 4; ++i)
#pragma unroll
    for (int j = 0; j < 4; ++j) {
      const int m = tn * 128 + wc + j * 16 + lr;
#pragma unroll
      for (int q = 0; q < 4; ++q) {
        const int n = tm * 128 + wr + i * 16 + lk * 4 + q;
        S[((size_t)h * BATCH + n) * BATCH + m] = 32.0f * acc[i][j][q];
      }
    }
}

// row-softmax; writes Ap packed [h][nt=4][ktm=8][8192]
__global__ __launch_bounds__(64) void softmax_kernel(
    const float* __restrict__ S, _Float16* __restrict__ Ap) {
  const int h = blockIdx.x >> 9, n = blockIdx.x & 511;
  const size_t r = (size_t)blockIdx.x * BATCH;
  const int l = threadIdx.x;
  float v[8];
  float mx = -1e30f;
#pragma unroll
  for (int i = 0; i < 8; ++i) { v[i] = S[r + i * 64 + l]; mx = fmaxf(mx, v[i]); }
#pragma unroll
  for (int off = 32; off; off >>= 1) mx = fmaxf(mx, __shfl_xor(mx, off));
  float sum = 0.f;
#pragma unroll
  for (int i = 0; i < 8; ++i) { v[i] = __expf(v[i] - mx); sum += v[i]; }
#pragma unroll
  for (int off = 32; off; off >>= 1) sum += __shfl_xor(sum, off);
  const float inv = 1.f / sum;
  const int row = n & 127;
  const int cbs = ((l >> 3) ^ (row & 7)) * 8 + (l & 7);
  const size_t base = (((size_t)h * 4 + (n >> 7)) * 8) * 8192 + row * 64 + cbs;
#pragma unroll
  for (int i = 0; i < 8; ++i)           // m-tile index = i
    Ap[base + (size_t)i * 8192] = (_Float16)(v[i] * inv);
}

// Out[n,h,e] = sum_m A[n,m] V[e,m]  (fp32 natural out)
__global__ __launch_bounds__(256) void pv_kernel(
    const _Float16* __restrict__ Ap, const _Float16* __restrict__ Vp,
    float* __restrict__ Out) {
  __shared__ __align__(16) _Float16 As[128 * 64];
  __shared__ __align__(16) _Float16 Bs[128 * 64];
  const int tid = threadIdx.x;
  const int l  = xcd_swz(blockIdx.x, 256);
  const int h  = l >> 5, bx = l & 31;
  const int tm = bx & 3, tn = bx >> 2;   // n-tile (4), e-tile (8)
  const int lane = tid & 63, w = tid >> 6;
  const int wr = (w >> 1) * 64, wc = (w & 1) * 64;
  const int lr = lane & 15, lk = lane >> 4;

  const char* ga = (const char*)(Ap + (((size_t)h * 4 + tm) * 8) * 8192);
  const char* gb = (const char*)(Vp + (((size_t)h * 8 + tn) * 8) * 8192);

  f32x4 acc[4][4] = {};
  gemm16p_core<8>(ga, gb, As, Bs, tid, wr, wc, lr, lk, acc);

#pragma unroll
  for (int i = 0; i < 4; ++i)
#pragma unroll
    for (int j = 0; j < 4; ++j) {
      const int e = tn * 128 + wc + j * 16 + lr;
#pragma unroll
      for (int q = 0; q < 4; ++q) {
        const int n = tm * 128 + wr + i * 16 + lk * 4 + q;
        Out[((size_t)n * HEADS + h) * DH + e] = acc[i][j][q];
      }
    }
}

}  // namespace

extern "C" void kernel_launch(void* const* d_in, const int* in_sizes, int n_in,
                              void* d_out, int out_size, void* d_ws, size_t ws_size,
                              hipStream_t stream) {
  (void)in_sizes; (void)n_in; (void)out_size; (void)ws_size;
  const float* q  = (const float*)d_in[0];
  const float* k  = (const float*)d_in[1];
  const float* v  = (const float*)d_in[2];
  const float* W1 = (const float*)d_in[3];
  const float* b1 = (const float*)d_in[4];
  const float* W2 = (const float*)d_in[5];
  const float* b2 = (const float*)d_in[6];
  const float* W3 = (const float*)d_in[7];
  const float* b3 = (const float*)d_in[8];
  float* out = (float*)d_out;

  // workspace (~96 MiB): packed tiles; S and Ap alias dead pack buffers
  _Float16* Xp = (_Float16*)d_ws;                 // 3*8*4*16*8192  = 12,582,912 h (25 MB)
  _Float16* Wp = Xp + (size_t)12582912;           // 3*8*8*16*8192  = 25,165,824 h (50 MB)
  _Float16* Qp = Wp + (size_t)25165824;           // 8*4*16*8192    =  4,194,304 h (8.4 MB)
  _Float16* Kp = Qp + (size_t)4194304;
  _Float16* Vp = Kp + (size_t)4194304;            // 8*8*8*8192
  float*    S  = (float*)Xp;                      // alias: Xp dead after proj (8.4 MB)
  _Float16* Ap = Wp;                              // alias: Wp dead after proj (4.2 MB)

  pack_kernel<<<dim3(288), dim3(256), 0, stream>>>(q, k, v, W1, W2, W3, Xp, Wp);
  proj_kernel<<<dim3(768), dim3(256), 0, stream>>>(Xp, Wp, b1, b2, b3, Qp, Kp, Vp);
  score_kernel<<<dim3(128), dim3(256), 0, stream>>>(Qp, Kp, S);
  softmax_kernel<<<dim3(HEADS * BATCH), dim3(64), 0, stream>>>(S, Ap);
  pv_kernel<<<dim3(256), dim3(256), 0, stream>>>(Ap, Vp, out);
}

// Round 13
// 116.233 us; speedup vs baseline: 1.0355x; 1.0355x over previous
//
#include <hip/hip_runtime.h>

typedef _Float16 half8 __attribute__((ext_vector_type(8)));
typedef _Float16 half4 __attribute__((ext_vector_type(4)));
typedef float f32x4 __attribute__((ext_vector_type(4)));

namespace {

constexpr int HEADS = 8;
constexpr int BATCH = 512;
constexpr int DH    = 1024;
constexpr int CHW   = 8192;

__device__ __forceinline__ int xcd_swz(int bid, int nwg) {
  const int q = nwg >> 3;  // grids are %8 == 0
  return (bid & 7) * q + (bid >> 3);
}

typedef __attribute__((address_space(3))) unsigned int lds_u32;
typedef const __attribute__((address_space(1))) unsigned int glb_u32;
__device__ __forceinline__ void gl_lds16(const void* g, void* l) {
  __builtin_amdgcn_global_load_lds((glb_u32*)g, (lds_u32*)l, 16, 0, 0);
}

__device__ __forceinline__ half4 cvt4(float4 a) {
  half4 r;
  r[0] = (_Float16)a.x; r[1] = (_Float16)a.y; r[2] = (_Float16)a.z; r[3] = (_Float16)a.w;
  return r;
}

// ---------------------------------------------------------------------------
// PACK: X (3x 512x8192 f32) and W (3x 8x1024x1024 f32) -> f16 tiles.
// Tile = 128 rows x 64 cols (16 KB), XOR bank-swizzle baked in.
// R13: row-sweep split 8x (16 rows/block) -> grid 2304 for latency hiding.
// ---------------------------------------------------------------------------
__global__ __launch_bounds__(256) void pack_kernel(
    const float* __restrict__ Xq, const float* __restrict__ Xk, const float* __restrict__ Xv,
    const float* __restrict__ W1, const float* __restrict__ W2, const float* __restrict__ W3,
    _Float16* __restrict__ Xp, _Float16* __restrict__ Wp) {
  const int lo = xcd_swz(blockIdx.x, 2304);
  const int l = lo % 288;            // original panel id
  const int r0 = (lo / 288) * 16;    // 16-row chunk within the panel
  const int t = threadIdx.x;
  const int kt = t >> 4;
  const int cbn = (t & 15) >> 1;
  const int hi  = (t & 1) * 4;
  const float* src;
  size_t srcStride;
  _Float16* dstBase;
  if (l < 192) {  // W: (z,h,et), rows contiguous
    const int z = l >> 6, rem = l & 63, h = rem >> 3, et = rem & 7;
    const float* W = (z == 0) ? W1 : (z == 1) ? W2 : W3;
    src = W + (size_t)h * DH * DH + (size_t)et * 128 * DH + t * 4;
    srcStride = DH;
    dstBase = Wp + ((((size_t)z * 8 + h) * 8 + et) * 16 + kt) * 8192;
  } else {        // X: (z,h,nt), rows at CHW stride
    const int l2 = l - 192;
    const int z = l2 >> 5, rem = l2 & 31, h = rem >> 2, nt = rem & 3;
    const float* X = (z == 0) ? Xq : (z == 1) ? Xk : Xv;
    src = X + (size_t)nt * 128 * CHW + (size_t)h * DH + t * 4;
    srcStride = CHW;
    dstBase = Xp + ((((size_t)z * 8 + h) * 4 + nt) * 16 + kt) * 8192;
  }
#pragma unroll 1
  for (int r = r0; r < r0 + 16; r += 4) {
    float4 v0 = *(const float4*)(src + (size_t)(r + 0) * srcStride);
    float4 v1 = *(const float4*)(src + (size_t)(r + 1) * srcStride);
    float4 v2 = *(const float4*)(src + (size_t)(r + 2) * srcStride);
    float4 v3 = *(const float4*)(src + (size_t)(r + 3) * srcStride);
    *(half4*)&dstBase[(r + 0) * 64 + (cbn ^ ((r + 0) & 7)) * 8 + hi] = cvt4(v0);
    *(half4*)&dstBase[(r + 1) * 64 + (cbn ^ ((r + 1) & 7)) * 8 + hi] = cvt4(v1);
    *(half4*)&dstBase[(r + 2) * 64 + (cbn ^ ((r + 2) & 7)) * 8 + hi] = cvt4(v2);
    *(half4*)&dstBase[(r + 3) * 64 + (cbn ^ ((r + 3) & 7)) * 8 + hi] = cvt4(v3);
  }
}

// ---------------------------------------------------------------------------
// f16 GEMM core on PACKED tiles: each K-step stages ONE contiguous 16-KB
// block per operand via global_load_lds (fully linear source). 128x128 tile,
// BK=64, 2 barriers/K-step, 32 KB LDS. ds_read applies the baked XOR.
// ---------------------------------------------------------------------------
template <int NT>
__device__ __forceinline__ void gemm16p_core(
    const char* ga, const char* gb,
    _Float16* As, _Float16* Bs,
    int tid, int wr, int wc, int lr, int lk, f32x4 (&acc)[4][4]) {
  const int off0 = tid * 16, off1 = 4096 + tid * 16;
  const int off2 = 8192 + tid * 16, off3 = 12288 + tid * 16;
#pragma unroll 1
  for (int t = 0; t < NT; ++t) {
    __syncthreads();
    gl_lds16(ga + off0, (char*)As + off0); gl_lds16(gb + off0, (char*)Bs + off0);
    gl_lds16(ga + off1, (char*)As + off1); gl_lds16(gb + off1, (char*)Bs + off1);
    gl_lds16(ga + off2, (char*)As + off2); gl_lds16(gb + off2, (char*)Bs + off2);
    gl_lds16(ga + off3, (char*)As + off3); gl_lds16(gb + off3, (char*)Bs + off3);
    ga += 16384; gb += 16384;
    __syncthreads();
    half8 a0[4], a1[4], b0[4], b1[4];
#pragma unroll
    for (int i = 0; i < 4; ++i) {
      const int row = wr + i * 16 + lr;
      a0[i] = *(const half8*)&As[row * 64 + ((lk    ) ^ (row & 7)) * 8];
      a1[i] = *(const half8*)&As[row * 64 + ((4 + lk) ^ (row & 7)) * 8];
    }
#pragma unroll
    for (int j = 0; j < 4; ++j) {
      const int row = wc + j * 16 + lr;
      b0[j] = *(const half8*)&Bs[row * 64 + ((lk    ) ^ (row & 7)) * 8];
      b1[j] = *(const half8*)&Bs[row * 64 + ((4 + lk) ^ (row & 7)) * 8];
    }
#pragma unroll
    for (int i = 0; i < 4; ++i)
#pragma unroll
      for (int j = 0; j < 4; ++j) {
        acc[i][j] = __builtin_amdgcn_mfma_f32_16x16x32_f16(a0[i], b0[j], acc[i][j], 0, 0, 0);
        acc[i][j] = __builtin_amdgcn_mfma_f32_16x16x32_f16(a1[i], b1[j], acc[i][j], 0, 0, 0);
      }
  }
}

// ---------------------------------------------------------------------------
// Fused Q/K/V projection on packed inputs. Outputs packed:
//   Qp/Kp[h][nt=4][kte=16][8192]   Vp[h][et=8][ktm=8][8192]
// ---------------------------------------------------------------------------
__global__ __launch_bounds__(256) void proj_kernel(
    const _Float16* __restrict__ Xp, const _Float16* __restrict__ Wp,
    const float* __restrict__ b1, const float* __restrict__ b2, const float* __restrict__ b3,
    _Float16* __restrict__ Qp, _Float16* __restrict__ Kp, _Float16* __restrict__ Vp) {
  __shared__ __align__(16) _Float16 As[128 * 64];
  __shared__ __align__(16) _Float16 Bs[128 * 64];
  const int tid = threadIdx.x;
  const int l  = xcd_swz(blockIdx.x, 768);
  const int z  = l >> 8, rem = l & 255;
  const int h  = rem >> 5, bx = rem & 31;
  const int tm = bx & 3, tn = bx >> 2;   // tm: n-tile (4), tn: e-tile (8)
  const float* bias = (z == 0) ? b1 : (z == 1) ? b2 : b3;

  const int lane = tid & 63, w = tid >> 6;
  const int wr = (w >> 1) * 64, wc = (w & 1) * 64;
  const int lr = lane & 15, lk = lane >> 4;

  const char* ga = (const char*)(Xp + ((((size_t)z * 8 + h) * 4 + tm) * 16) * 8192);
  const char* gb = (const char*)(Wp + ((((size_t)z * 8 + h) * 8 + tn) * 16) * 8192);

  f32x4 acc[4][4] = {};
  gemm16p_core<16>(ga, gb, As, Bs, tid, wr, wc, lr, lk, acc);

  if (z != 2) {
    _Float16* P = (z == 0) ? Qp : Kp;
#pragma unroll
    for (int i = 0; i < 4; ++i)
#pragma unroll
      for (int j = 0; j < 4; ++j) {
        const int colj = wc + j * 16 + lr;         // e within 128-tile
        const int e = tn * 128 + colj;
        const float bb = bias[h * DH + e];
        const int kte = tn * 2 + (colj >> 6);
        const int c64 = colj & 63;
        const int cbn = c64 >> 3;
#pragma unroll
        for (int q = 0; q < 4; ++q) {
          const int row = wr + i * 16 + lk * 4 + q;  // n within 128-tile
          const float val = acc[i][j][q] + bb;
          P[(((size_t)h * 4 + tm) * 16 + kte) * 8192 +
            row * 64 + ((cbn ^ (row & 7)) * 8) + (c64 & 7)] = (_Float16)val;
        }
      }
  } else {
#pragma unroll
    for (int i = 0; i < 4; ++i)
#pragma unroll
      for (int j = 0; j < 4; ++j) {
        const int row_v = wc + j * 16 + lr;        // e within 128-tile (Vp row)
        const float bb = bias[h * DH + tn * 128 + row_v];
#pragma unroll
        for (int q = 0; q < 4; ++q) {
          const int n = tm * 128 + wr + i * 16 + lk * 4 + q;  // global m index
          const float val = acc[i][j][q] + bb;
          const int c64 = n & 63;
          const int cbn = c64 >> 3;
          Vp[(((size_t)h * 8 + tn) * 8 + (n >> 6)) * 8192 +
             row_v * 64 + ((cbn ^ (row_v & 7)) * 8) + (n & 7)] = (_Float16)val;
        }
      }
  }
}

// S[h,n,m] = 32 * sum_e Q[n,e] K[m,e]  (fp32 natural rows, for softmax)
__global__ __launch_bounds__(256) void score_kernel(
    const _Float16* __restrict__ Qp, const _Float16* __restrict__ Kp,
    float* __restrict__ S) {
  __shared__ __align__(16) _Float16 As[128 * 64];
  __shared__ __align__(16) _Float16 Bs[128 * 64];
  const int tid = threadIdx.x;
  const int l  = xcd_swz(blockIdx.x, 128);
  const int h  = l >> 4, bx = l & 15;
  const int tm = bx & 3, tn = bx >> 2;   // n-tile, m-tile
  const int lane = tid & 63, w = tid >> 6;
  const int wr = (w >> 1) * 64, wc = (w & 1) * 64;
  const int lr = lane & 15, lk = lane >> 4;

  const char* ga = (const char*)(Qp + (((size_t)h * 4 + tm) * 16) * 8192);
  const char* gb = (const char*)(Kp + (((size_t)h * 4 + tn) * 16) * 8192);

  f32x4 acc[4][4] = {};
  gemm16p_core<16>(ga, gb, As, Bs, tid, wr, wc, lr, lk, acc);

#pragma unroll
  for (int i = 0; i < 4; ++i)
#pragma unroll
    for (int j = 0; j < 4; ++j) {
      const int m = tn * 128 + wc + j * 16 + lr;
#pragma unroll
      for (int q = 0; q < 4; ++q) {
        const int n = tm * 128 + wr + i * 16 + lk * 4 + q;
        S[((size_t)h * BATCH + n) * BATCH + m] = 32.0f * acc[i][j][q];
      }
    }
}

// row-softmax; writes Ap packed [h][nt=4][ktm=8][8192]
__global__ __launch_bounds__(64) void softmax_kernel(
    const float* __restrict__ S, _Float16* __restrict__ Ap) {
  const int h = blockIdx.x >> 9, n = blockIdx.x & 511;
  const size_t r = (size_t)blockIdx.x * BATCH;
  const int l = threadIdx.x;
  float v[8];
  float mx = -1e30f;
#pragma unroll
  for (int i = 0; i < 8; ++i) { v[i] = S[r + i * 64 + l]; mx = fmaxf(mx, v[i]); }
#pragma unroll
  for (int off = 32; off; off >>= 1) mx = fmaxf(mx, __shfl_xor(mx, off));
  float sum = 0.f;
#pragma unroll
  for (int i = 0; i < 8; ++i) { v[i] = __expf(v[i] - mx); sum += v[i]; }
#pragma unroll
  for (int off = 32; off; off >>= 1) sum += __shfl_xor(sum, off);
  const float inv = 1.f / sum;
  const int row = n & 127;
  const int cbs = ((l >> 3) ^ (row & 7)) * 8 + (l & 7);
  const size_t base = (((size_t)h * 4 + (n >> 7)) * 8) * 8192 + row * 64 + cbs;
#pragma unroll
  for (int i = 0; i < 8; ++i)           // m-tile index = i
    Ap[base + (size_t)i * 8192] = (_Float16)(v[i] * inv);
}

// Out[n,h,e] = sum_m A[n,m] V[e,m]  (fp32 natural out)
__global__ __launch_bounds__(256) void pv_kernel(
    const _Float16* __restrict__ Ap, const _Float16* __restrict__ Vp,
    float* __restrict__ Out) {
  __shared__ __align__(16) _Float16 As[128 * 64];
  __shared__ __align__(16) _Float16 Bs[128 * 64];
  const int tid = threadIdx.x;
  const int l  = xcd_swz(blockIdx.x, 256);
  const int h  = l >> 5, bx = l & 31;
  const int tm = bx & 3, tn = bx >> 2;   // n-tile (4), e-tile (8)
  const int lane = tid & 63, w = tid >> 6;
  const int wr = (w >> 1) * 64, wc = (w & 1) * 64;
  const int lr = lane & 15, lk = lane >> 4;

  const char* ga = (const char*)(Ap + (((size_t)h * 4 + tm) * 8) * 8192);
  const char* gb = (const char*)(Vp + (((size_t)h * 8 + tn) * 8) * 8192);

  f32x4 acc[4][4] = {};
  gemm16p_core<8>(ga, gb, As, Bs, tid, wr, wc, lr, lk, acc);

#pragma unroll
  for (int i = 0; i < 4; ++i)
#pragma unroll
    for (int j = 0; j < 4; ++j) {
      const int e = tn * 128 + wc + j * 16 + lr;
#pragma unroll
      for (int q = 0; q < 4; ++q) {
        const int n = tm * 128 + wr + i * 16 + lk * 4 + q;
        Out[((size_t)n * HEADS + h) * DH + e] = acc[i][j][q];
      }
    }
}

}  // namespace

extern "C" void kernel_launch(void* const* d_in, const int* in_sizes, int n_in,
                              void* d_out, int out_size, void* d_ws, size_t ws_size,
                              hipStream_t stream) {
  (void)in_sizes; (void)n_in; (void)out_size; (void)ws_size;
  const float* q  = (const float*)d_in[0];
  const float* k  = (const float*)d_in[1];
  const float* v  = (const float*)d_in[2];
  const float* W1 = (const float*)d_in[3];
  const float* b1 = (const float*)d_in[4];
  const float* W2 = (const float*)d_in[5];
  const float* b2 = (const float*)d_in[6];
  const float* W3 = (const float*)d_in[7];
  const float* b3 = (const float*)d_in[8];
  float* out = (float*)d_out;

  // workspace (~96 MiB): packed tiles; S and Ap alias dead pack buffers
  _Float16* Xp = (_Float16*)d_ws;                 // 3*8*4*16*8192  (25 MB)
  _Float16* Wp = Xp + (size_t)12582912;           // 3*8*8*16*8192  (50 MB)
  _Float16* Qp = Wp + (size_t)25165824;           // 8*4*16*8192    (8.4 MB)
  _Float16* Kp = Qp + (size_t)4194304;
  _Float16* Vp = Kp + (size_t)4194304;            // 8*8*8*8192
  float*    S  = (float*)Xp;                      // alias: Xp dead after proj
  _Float16* Ap = Wp;                              // alias: Wp dead after proj

  pack_kernel<<<dim3(2304), dim3(256), 0, stream>>>(q, k, v, W1, W2, W3, Xp, Wp);
  proj_kernel<<<dim3(768), dim3(256), 0, stream>>>(Xp, Wp, b1, b2, b3, Qp, Kp, Vp);
  score_kernel<<<dim3(128), dim3(256), 0, stream>>>(Qp, Kp, S);
  softmax_kernel<<<dim3(HEADS * BATCH), dim3(64), 0, stream>>>(S, Ap);
  pv_kernel<<<dim3(256), dim3(256), 0, stream>>>(Ap, Vp, out);
}